// Round 5
// baseline (352.402 us; speedup 1.0000x reference)
//
#include <hip/hip_runtime.h>
#include <math.h>

#define BB 8
#define NPTS 80000
#define KK 5
#define FF 20
#define GG 128                 // blocks per batch -> 1024 blocks = 4 blocks/CU exactly
#define TILE 128               // two points per lane
#define NTILES (NPTS / TILE)   // 625, exact
#define PSTRIDE 48             // padded partial row: 20 s1 + 20 s2 + 1 s0 + pad

// workspace layout (float offsets) -- small params/coefs only
#define WS_CM 0          // cur means  [B,K,F] = 800
#define WS_CV 800        // cur var    = 800
#define WS_CP 1600       // cur pi     = 40
#define WS_A  1640       // A coef     = 40
#define WS_D  1680       // d coef     = 800
#define WS_E  2480       // e coef     = 800

// Raw barrier: drain LDS ops (cross-wave lls visibility) but leave global
// loads (prefetch touches) in flight. __syncthreads() would emit
// s_waitcnt vmcnt(0) and expose the prefetch latency AT the barrier.
#define WAIT_BAR() asm volatile("s_waitcnt lgkmcnt(0)\n\ts_barrier" ::: "memory")

__device__ __forceinline__ float rfl(float x) {   // lane0 value -> SGPR
    return __uint_as_float(__builtin_amdgcn_readfirstlane(__float_as_uint(x)));
}

// ---- E-step with fused M-step prologue ----
// MODE 0: coefs from raw inputs (first E-step); accumulate partials -> pout
// MODE 1: coefs rebuilt from PREVIOUS iteration's partials (pin), i.e. the
//         M-step update is fused into this kernel's prologue; accumulate -> pout
// MODE 3: coefs from ws (written by update_kernel); write ll/post outputs
// pin/pout are distinct buffers (ping-pong): a fused kernel reads pin in its
// prologue while other blocks may already write pout -> must not alias.
template <int MODE>
__global__ __launch_bounds__(320) void estep_kernel(
        const float* __restrict__ data,
        const float* __restrict__ in_means, const float* __restrict__ in_var,
        const float* __restrict__ in_pi,
        const float* __restrict__ ws,
        const float* __restrict__ pin, float* __restrict__ pout,
        float* __restrict__ out_ll, float* __restrict__ out_post) {
    __shared__ float lls[2][KK][TILE];        // 5 KB: z exchange, double-buffered
    __shared__ float coefs[KK][2 * FF + 1];   // dk | ek | A broadcast buffer
    __shared__ float s0s[KK];

    const int b    = blockIdx.x / GG;
    const int g    = blockIdx.x % GG;
    const int tid  = threadIdx.x;
    const int w    = __builtin_amdgcn_readfirstlane(tid >> 6);   // cluster k
    const int lane = tid & 63;
    const int bk   = b * KK + w;

    float dk[FF], ek[FF];   // wave-uniform -> SGPRs (s_load or readfirstlane)
    float Ak;

    if (MODE == 3) {
        Ak = (ws + WS_A)[bk];                    // uniform addr -> s_load
#pragma unroll
        for (int f = 0; f < FF; ++f) {
            dk[f] = (ws + WS_D)[bk * FF + f];
            ek[f] = (ws + WS_E)[bk * FF + f];
        }
    } else {
        if (MODE == 0) {
            // coefs straight from the input params (was prepare_kernel)
            float t1 = 0.f, t2 = 0.f;
            if (lane < FF) {
                float v = in_var[bk * FF + lane];
                float m = in_means[bk * FF + lane];
                float ic = 1.f / (v + 1e-6f);
                coefs[w][lane]      = ic * m;
                coefs[w][FF + lane] = -0.5f * ic;
                t1 = logf(6.283185307179586f * v);
                t2 = ic * m * m;
            }
#pragma unroll
            for (int off = 1; off < 64; off <<= 1) {
                t1 += __shfl_xor(t1, off);
                t2 += __shfl_xor(t2, off);
            }
            if (lane == 0)
                coefs[w][2 * FF] = logf(in_pi[bk]) - 0.5f * t1 - 0.5f * t2;
            __syncthreads();
        } else {
            // MODE 1: fused M-step. Every block redundantly reduces pin for
            // its batch: wave w, lane<48 sums slot `lane` over GG rows
            // (coalesced 192B rows, 4 split accumulators for MLP).
            float sv = 0.f;
            if (lane < PSTRIDE) {
                const float* base = pin + (size_t)bk * GG * PSTRIDE + lane;
                float a0 = 0.f, a1 = 0.f, a2 = 0.f, a3 = 0.f;
                for (int gg = 0; gg < GG; gg += 4) {
                    a0 += base[(size_t)(gg    ) * PSTRIDE];
                    a1 += base[(size_t)(gg + 1) * PSTRIDE];
                    a2 += base[(size_t)(gg + 2) * PSTRIDE];
                    a3 += base[(size_t)(gg + 3) * PSTRIDE];
                }
                sv = (a0 + a1) + (a2 + a3);
            }
            float s0 = __shfl(sv, 2 * FF);
            if (lane == 0) s0s[w] = s0;
            __syncthreads();
            float tot = s0s[0] + s0s[1] + s0s[2] + s0s[3] + s0s[4];
            float den = s0 + 1e-7f;
            float m   = sv / den;                      // lanes 0..19: S1[f]/den
            float s2f = __shfl(sv, FF + (lane % FF));  // S2[f]
            float var = (s2f - 2.f * m * sv + m * m * s0) / den + 1e-6f;
            float pr  = (s0 / (float)NPTS) / fmaxf(tot / (float)NPTS, 1e-12f);
            float ic  = 1.f / (var + 1e-6f);
            float t1 = 0.f, t2 = 0.f;
            if (lane < FF) {
                coefs[w][lane]      = ic * m;
                coefs[w][FF + lane] = -0.5f * ic;
                t1 = logf(6.283185307179586f * var);
                t2 = ic * m * m;
            }
#pragma unroll
            for (int off = 1; off < 64; off <<= 1) {
                t1 += __shfl_xor(t1, off);
                t2 += __shfl_xor(t2, off);
            }
            if (lane == 0)
                coefs[w][2 * FF] = logf(pr) - 0.5f * t1 - 0.5f * t2;
            __syncthreads();
        }
        // broadcast LDS coefs -> SGPR arrays (uniform addr read + readfirstlane)
#pragma unroll
        for (int f = 0; f < FF; ++f) {
            dk[f] = rfl(coefs[w][f]);
            ek[f] = rfl(coefs[w][FF + f]);
        }
        Ak = rfl(coefs[w][2 * FF]);
    }

    constexpr bool ACC = (MODE != 3);
    float s0a = 0.f, s1[FF], s2[FF];
    if (ACC) {
#pragma unroll
        for (int f = 0; f < FF; ++f) { s1[f] = 0.f; s2[f] = 0.f; }
    }

    const float* dbase = data + (size_t)b * NPTS * FF;
    int pb = 0;

    for (int t = g; t < NTILES; t += GG) {
        // two lane-owned points: A = t*128+lane, B = A+64 (5 dwordx4 each)
        const float* xpA = dbase + ((size_t)t * TILE + lane) * FF;
        const float* xpB = xpA + 64 * FF;
        float4 a0 = ((const float4*)xpA)[0];
        float4 a1 = ((const float4*)xpA)[1];
        float4 a2 = ((const float4*)xpA)[2];
        float4 a3 = ((const float4*)xpA)[3];
        float4 a4 = ((const float4*)xpA)[4];
        float4 c0 = ((const float4*)xpB)[0];
        float4 c1 = ((const float4*)xpB)[1];
        float4 c2 = ((const float4*)xpB)[2];
        float4 c3 = ((const float4*)xpB)[3];
        float4 c4 = ((const float4*)xpB)[4];

        // prefetch touches for tile t+GG (stay outstanding across WAIT_BAR)
        float pfA = 0.f, pfB = 0.f;
        const int tn = t + GG;
        if (tn < NTILES) {
            pfA = dbase[((size_t)tn * TILE + lane) * FF];
            pfB = dbase[((size_t)tn * TILE + 64 + lane) * FF];
        }

        float xA[FF], xB[FF];
        xA[0]=a0.x; xA[1]=a0.y; xA[2]=a0.z; xA[3]=a0.w;
        xA[4]=a1.x; xA[5]=a1.y; xA[6]=a1.z; xA[7]=a1.w;
        xA[8]=a2.x; xA[9]=a2.y; xA[10]=a2.z; xA[11]=a2.w;
        xA[12]=a3.x; xA[13]=a3.y; xA[14]=a3.z; xA[15]=a3.w;
        xA[16]=a4.x; xA[17]=a4.y; xA[18]=a4.z; xA[19]=a4.w;
        xB[0]=c0.x; xB[1]=c0.y; xB[2]=c0.z; xB[3]=c0.w;
        xB[4]=c1.x; xB[5]=c1.y; xB[6]=c1.z; xB[7]=c1.w;
        xB[8]=c2.x; xB[9]=c2.y; xB[10]=c2.z; xB[11]=c2.w;
        xB[12]=c3.x; xB[13]=c3.y; xB[14]=c3.z; xB[15]=c3.w;
        xB[16]=c4.x; xB[17]=c4.y; xB[18]=c4.z; xB[19]=c4.w;

        float zA = Ak, zB = Ak;
#pragma unroll
        for (int f = 0; f < FF; ++f) {
            zA = fmaf(xA[f], fmaf(ek[f], xA[f], dk[f]), zA);
            zB = fmaf(xB[f], fmaf(ek[f], xB[f], dk[f]), zB);
        }
        lls[pb][w][lane]      = zA;
        lls[pb][w][lane + 64] = zB;
        WAIT_BAR();                 // lls visible; prefetch still in flight

        float l0 = lls[pb][0][lane], l1 = lls[pb][1][lane], l2 = lls[pb][2][lane],
              l3 = lls[pb][3][lane], l4 = lls[pb][4][lane];
        float mxA = fmaxf(fmaxf(fmaxf(l0, l1), fmaxf(l2, l3)), l4);
        float e0 = __expf(l0 - mxA), e1 = __expf(l1 - mxA), e2 = __expf(l2 - mxA),
              e3 = __expf(l3 - mxA), e4 = __expf(l4 - mxA);
        float invA = 1.f / (e0 + e1 + e2 + e3 + e4);
        float ewA  = (w == 0) ? e0 : (w == 1) ? e1 : (w == 2) ? e2 : (w == 3) ? e3 : e4;
        float postA = ewA * invA;

        float m0 = lls[pb][0][lane+64], m1 = lls[pb][1][lane+64], m2 = lls[pb][2][lane+64],
              m3 = lls[pb][3][lane+64], m4 = lls[pb][4][lane+64];
        float mxB = fmaxf(fmaxf(fmaxf(m0, m1), fmaxf(m2, m3)), m4);
        float f0 = __expf(m0 - mxB), f1 = __expf(m1 - mxB), f2 = __expf(m2 - mxB),
              f3 = __expf(m3 - mxB), f4 = __expf(m4 - mxB);
        float invB = 1.f / (f0 + f1 + f2 + f3 + f4);
        float ewB  = (w == 0) ? f0 : (w == 1) ? f1 : (w == 2) ? f2 : (w == 3) ? f3 : f4;
        float postB = ewB * invB;

        if (!ACC) {
            size_t oA = ((size_t)b * NPTS + (size_t)t * TILE + lane) * KK + w;
            out_ll[oA]   = zA;
            out_post[oA] = postA;
            size_t oB = oA + (size_t)64 * KK;
            out_ll[oB]   = zB;
            out_post[oB] = postB;
        } else {
            s0a += postA + postB;
#pragma unroll
            for (int f = 0; f < FF; ++f) {
                float qA = postA * xA[f];
                float qB = postB * xB[f];
                s1[f] += qA + qB;
                s2[f] = fmaf(qA, xA[f], s2[f]);
                s2[f] = fmaf(qB, xB[f], s2[f]);
            }
        }
        asm volatile("" :: "v"(pfA), "v"(pfB));   // keep prefetch alive
        pb ^= 1;
    }

    if (ACC) {
#pragma unroll
        for (int off = 32; off > 0; off >>= 1) {
            s0a += __shfl_down(s0a, off);
#pragma unroll
            for (int f = 0; f < FF; ++f) {
                s1[f] += __shfl_down(s1[f], off);
                s2[f] += __shfl_down(s2[f], off);
            }
        }
        if (lane == 0) {
            float* row = pout + ((size_t)bk * GG + g) * PSTRIDE;
#pragma unroll
            for (int f = 0; f < FF; ++f) { row[f] = s1[f]; row[FF + f] = s2[f]; }
            row[2 * FF] = s0a;
        }
    }
}

// ---- final reduce + M-step: writes om/ov/op AND ws coefs for the last E-step ----
__global__ __launch_bounds__(512) void update_kernel(const float* __restrict__ partials,
                                                     float* __restrict__ ws,
                                                     float* __restrict__ om,
                                                     float* __restrict__ ov,
                                                     float* __restrict__ op) {
    __shared__ float shA[8][PSTRIDE];
    __shared__ float shB[8 * KK];
    const int bk   = blockIdx.x;          // b*KK + k
    const int b    = bk / KK;
    const int tid  = threadIdx.x;
    const int w8   = tid >> 6;
    const int lane = tid & 63;

    if (lane < PSTRIDE) {
        const float* base = partials + (size_t)bk * GG * PSTRIDE + lane;
        float sv = 0.f;
        for (int gg = w8; gg < GG; gg += 8) sv += base[(size_t)gg * PSTRIDE];
        shA[w8][lane] = sv;
    }
    if (tid < 8 * KK) {
        const int kp = tid >> 3, j = tid & 7;
        const float* cb = partials + (size_t)(b * KK + kp) * GG * PSTRIDE + 2 * FF;
        float s = 0.f;
        for (int gg = j; gg < GG; gg += 8) s += cb[(size_t)gg * PSTRIDE];
        shB[tid] = s;
    }
    __syncthreads();

    if (tid < 64) {
        float svt = 0.f;
        if (lane < PSTRIDE) {
            svt = (shA[0][lane] + shA[1][lane]) + (shA[2][lane] + shA[3][lane])
                + (shA[4][lane] + shA[5][lane]) + (shA[6][lane] + shA[7][lane]);
        }

        float tb = (lane < 8 * KK) ? shB[lane] : 0.f;
#pragma unroll
        for (int off = 32; off > 0; off >>= 1) tb += __shfl_xor(tb, off);

        float s0  = __shfl(svt, 2 * FF);
        float den = s0 + 1e-7f;
        float m   = svt / den;
        float s2f = __shfl(svt, FF + (lane % FF));
        float var = (s2f - 2.f * m * svt + m * m * s0) / den + 1e-6f;

        if (lane < FF) {
            om[bk * FF + lane] = m;
            ov[bk * FF + lane] = var;
        }

        float pr = (s0 / (float)NPTS) / fmaxf(tb / (float)NPTS, 1e-12f);
        if (lane == 0) op[bk] = pr;

        float ic = 1.f / (var + 1e-6f);
        if (lane < FF) {
            (ws + WS_D)[bk * FF + lane] = ic * m;
            (ws + WS_E)[bk * FF + lane] = -0.5f * ic;
        }
        float t1 = (lane < FF) ? logf(6.283185307179586f * var) : 0.f;
        float t2 = (lane < FF) ? ic * m * m : 0.f;
#pragma unroll
        for (int off = 1; off < 64; off <<= 1) {
            t1 += __shfl_xor(t1, off);
            t2 += __shfl_xor(t2, off);
        }
        if (lane == 0)
            (ws + WS_A)[bk] = logf(pr) - 0.5f * t1 - 0.5f * t2;
    }
}

extern "C" void kernel_launch(void* const* d_in, const int* in_sizes, int n_in,
                              void* d_out, int out_size, void* d_ws, size_t ws_size,
                              hipStream_t stream) {
    const float* data     = (const float*)d_in[0];
    const float* in_means = (const float*)d_in[1];
    const float* in_var   = (const float*)d_in[2];
    const float* in_pi    = (const float*)d_in[3];
    float* ws  = (float*)d_ws;
    float* out = (float*)d_out;

    float* out_ll   = out;
    float* out_post = out + (size_t)BB * NPTS * KK;
    float* om       = out + 2 * (size_t)BB * NPTS * KK;
    float* ov       = om + BB * KK * FF;
    float* op       = ov + BB * KK * FF;

    // ping-pong partial buffers (983 KB each) in the not-yet-needed ll region
    // (12.8 MB); the final E-step fully overwrites both.
    float* P0 = out_ll;
    float* P1 = out_ll + 262144;

    // it0: coefs from inputs, write P0
    estep_kernel<0><<<BB * GG, 320, 0, stream>>>(data, in_means, in_var, in_pi,
                                                 ws, nullptr, P0, nullptr, nullptr);
    // it1..4: fused update of previous partials; ping-pong P0/P1
    estep_kernel<1><<<BB * GG, 320, 0, stream>>>(data, nullptr, nullptr, nullptr,
                                                 ws, P0, P1, nullptr, nullptr);
    estep_kernel<1><<<BB * GG, 320, 0, stream>>>(data, nullptr, nullptr, nullptr,
                                                 ws, P1, P0, nullptr, nullptr);
    estep_kernel<1><<<BB * GG, 320, 0, stream>>>(data, nullptr, nullptr, nullptr,
                                                 ws, P0, P1, nullptr, nullptr);
    estep_kernel<1><<<BB * GG, 320, 0, stream>>>(data, nullptr, nullptr, nullptr,
                                                 ws, P1, P0, nullptr, nullptr);
    // final M-step (it4 partials in P0): writes om/ov/op + ws coefs
    update_kernel<<<BB * KK, 512, 0, stream>>>(P0, ws, om, ov, op);
    // final E-step: write ll/post with post-loop params
    estep_kernel<3><<<BB * GG, 320, 0, stream>>>(data, nullptr, nullptr, nullptr,
                                                 ws, nullptr, nullptr, out_ll, out_post);
}